// Round 1
// 412.013 us; speedup vs baseline: 1.1702x; 1.1702x over previous
//
#include <hip/hip_runtime.h>

#define U_    128
#define DIN   10240
#define RANK  320
#define NS    32
#define NTOT  384          // 320 (t) + 32 (B) + 32 (C)

// -------------------------------------------------------------------------
// Kernel 0: transpose x[128,10240] -> xT[10240,128] so GEMM vector loads
// along u are coalesced. 10.5 MB traffic, ~2 us. (unchanged)
// -------------------------------------------------------------------------
__global__ __launch_bounds__(256) void transpose_kernel(
    const float* __restrict__ x, float* __restrict__ xT)
{
    __shared__ float tile[32][33];
    int kb = blockIdx.x * 32, ub = blockIdx.y * 32;
    int tx = threadIdx.x, ty = threadIdx.y;      // (32, 8)
#pragma unroll
    for (int i = 0; i < 32; i += 8)
        tile[ty + i][tx] = x[(size_t)(ub + ty + i) * DIN + kb + tx];
    __syncthreads();
#pragma unroll
    for (int i = 0; i < 32; i += 8)
        xT[(size_t)(kb + ty + i) * U_ + ub + tx] = tile[tx][ty + i];
}

// -------------------------------------------------------------------------
// Kernel 1: gemmA — partial[kc][n][u] = sum_{k in chunk} xT[k,u] * W[k,n]
// R1 fix: 64-thread 1-wave blocks at 0.75 waves/SIMD were latency-bound on
// cold W-row loads (~300-800 cyc exposed per k-iter, no TLP).
//   - 128-thread blocks (2 waves cover all 128 u): each W element read by
//     ONE block (was 2), second wave hits L1 -> compulsory W traffic halved.
//   - KCC 32 -> 64: 768 blocks x 2 waves = 1536 waves = 1.5/SIMD of TLP.
//   - unroll 4: four W-row loads in flight per wave.
//   - XCD swizzle: the 12 nt-blocks sharing one xT k-chunk (80 KB) land on
//     the same XCD's L2 (ids congruent mod 8).
// -------------------------------------------------------------------------
template<int KCC>
__global__ __launch_bounds__(128) void gemmA_kernel(
    const float* __restrict__ xT,
    const float* __restrict__ Wd, const float* __restrict__ Wb,
    const float* __restrict__ Wc,
    float* __restrict__ partial)
{
    int b     = blockIdx.x;            // 12 nt * KCC kc, XCD-swizzled
    int kc_lo = b & 7;
    int rest  = b >> 3;
    int nt    = rest % 12;
    int kc    = (rest / 12) * 8 + kc_lo;
    int u     = threadIdx.x;           // 0..127
    int n0    = nt * 32;

    const float* W; int ldw, c0;
    if (nt < 10)       { W = Wd; ldw = RANK; c0 = n0; }
    else if (nt == 10) { W = Wb; ldw = NS;   c0 = 0;  }
    else               { W = Wc; ldw = NS;   c0 = 0;  }

    float acc[32];
#pragma unroll
    for (int j = 0; j < 32; ++j) acc[j] = 0.f;

    constexpr int KCHUNK = DIN / KCC;
    int k0 = kc * KCHUNK;
    const float* Wp = W  + (size_t)k0 * ldw + c0;
    const float* xp = xT + (size_t)k0 * U_ + u;

#pragma unroll 4
    for (int k = 0; k < KCHUNK; ++k) {
        float xv = xp[(size_t)k * U_];           // coalesced 512 B / block
#pragma unroll
        for (int j = 0; j < 32; ++j)
            acc[j] += xv * Wp[(size_t)k * ldw + j];  // block-uniform -> s_load
    }

    float* out = partial + (size_t)kc * (NTOT * U_) + (size_t)n0 * U_ + u;
#pragma unroll
    for (int j = 0; j < 32; ++j)
        out[(size_t)j * U_] = acc[j];            // coalesced, no atomics
}

// -------------------------------------------------------------------------
// Kernel 2: reduce KCC k-chunk partials -> tT[320,128], B[128,32], C[128,32].
// KCC=64: 12.6 MB read (L2/L3-resident), 0.2 MB write.
// -------------------------------------------------------------------------
template<int KCC>
__global__ __launch_bounds__(256) void reduce_kernel(
    const float* __restrict__ partial, float* __restrict__ tT,
    float* __restrict__ Bc, float* __restrict__ Cc)
{
    int e = blockIdx.x * 256 + threadIdx.x;      // 0..49151
    float s = 0.f;
#pragma unroll 8
    for (int kc = 0; kc < KCC; ++kc)
        s += partial[(size_t)kc * (NTOT * U_) + e];
    int n = e >> 7, u = e & 127;                 // e = n*128 + u
    if (n < RANK)            tT[e] = s;
    else if (n < RANK + NS)  Bc[u * NS + (n - RANK)] = s;
    else                     Cc[u * NS + (n - RANK - NS)] = s;
}

// -------------------------------------------------------------------------
// Kernel 3: delta = softplus(t @ W_dt + b_dt).
// R1 fix: 640 1-wave blocks were latency-bound on Wdt column loads.
//   - u-tile 32 -> 16: grid 160x8 = 1280 waves = 1.25/SIMD.
//   - unroll 4: 4 Wdt row-loads in flight.
//   - ut-blocks sharing a Wdt d-slice have ids differing by 160 (== 0 mod 8)
//     -> already co-resident on one XCD; 7 of 8 re-reads are L2 hits.
// -------------------------------------------------------------------------
__global__ __launch_bounds__(64) void delta_kernel(
    const float* __restrict__ tT, const float* __restrict__ Wdt,
    const float* __restrict__ b_dt, float* __restrict__ delta)
{
    int b   = blockIdx.x;                        // 160 dt * 8 ut
    int dt_ = b % 160, ut = b / 160;
    int d   = dt_ * 64 + threadIdx.x;
    int u0  = ut * 16;

    float bias = b_dt[d];
    float acc[16];
#pragma unroll
    for (int i = 0; i < 16; ++i) acc[i] = bias;

#pragma unroll 4
    for (int r = 0; r < RANK; ++r) {
        float w = Wdt[(size_t)r * DIN + d];      // coalesced 256 B v_load
        const float* tp = tT + r * U_ + u0;
#pragma unroll
        for (int i = 0; i < 16; ++i)
            acc[i] += w * tp[i];                 // block-uniform -> s_load
    }
#pragma unroll
    for (int i = 0; i < 16; ++i) {
        float z = acc[i];
        float sp = (z > 20.f) ? z : log1pf(__expf(z));
        delta[(size_t)(u0 + i) * DIN + d] = sp;
    }
}

// -------------------------------------------------------------------------
// Kernel 4: state update (memory-bound, ~353 MB HBM). UNCHANGED (control).
// -------------------------------------------------------------------------
__global__ __launch_bounds__(256) void ssm_kernel(
    const float* __restrict__ x, const float* __restrict__ h,
    const float* __restrict__ delta,
    const float* __restrict__ Bc, const float* __restrict__ Cc,
    const float* __restrict__ A, const float* __restrict__ Dvec,
    float* __restrict__ y, float* __restrict__ hnew)
{
    int idx4 = blockIdx.x * 256 + threadIdx.x;   // float4 index
    int n4 = idx4 & 7;
    int ud = idx4 >> 3;
    int d = ud % DIN;
    int u = ud / DIN;

    float dlt = delta[ud];
    float xv  = x[ud];

    float4 hv = ((const float4*)h)[idx4];
    float4 av = ((const float4*)A)[(size_t)d * 8 + n4];
    float4 bv = ((const float4*)Bc)[u * 8 + n4];
    float4 cv = ((const float4*)Cc)[u * 8 + n4];

    float dx = dlt * xv;
    float4 hn;
    hn.x = __expf(dlt * av.x) * hv.x + dx * bv.x;
    hn.y = __expf(dlt * av.y) * hv.y + dx * bv.y;
    hn.z = __expf(dlt * av.z) * hv.z + dx * bv.z;
    hn.w = __expf(dlt * av.w) * hv.w + dx * bv.w;

    ((float4*)hnew)[idx4] = hn;

    float p = hn.x * cv.x + hn.y * cv.y + hn.z * cv.z + hn.w * cv.w;
    p += __shfl_xor(p, 4, 8);
    p += __shfl_xor(p, 2, 8);
    p += __shfl_xor(p, 1, 8);
    if (n4 == 0)
        y[ud] = p + Dvec[d] * xv;
}

// -------------------------------------------------------------------------
extern "C" void kernel_launch(void* const* d_in, const int* in_sizes, int n_in,
                              void* d_out, int out_size, void* d_ws, size_t ws_size,
                              hipStream_t stream)
{
    const float* x   = (const float*)d_in[0];
    const float* h   = (const float*)d_in[1];
    const float* Wd  = (const float*)d_in[2];
    const float* Wdt = (const float*)d_in[3];
    const float* bdt = (const float*)d_in[4];
    const float* Wb  = (const float*)d_in[5];
    const float* Wc  = (const float*)d_in[6];
    const float* A   = (const float*)d_in[7];
    const float* Dv  = (const float*)d_in[8];

    // KCC=64 needs ws = 1310720 + 64*384*128 + 49152 = 4,505,600 floats (18 MB).
    // Fall back to KCC=32 (11.7 MB) if the workspace is smaller.
    const bool big = ws_size >= (size_t)4505600 * 4;
    const size_t partial_elems = (size_t)(big ? 64 : 32) * NTOT * U_;

    float* ws      = (float*)d_ws;
    float* xT      = ws;                         // 10240*128 = 1310720
    float* partial = ws + 1310720;               // KCC*384*128
    float* delta   = partial;                    // ALIAS: partial dead after reduce
    float* tT      = partial + partial_elems;    // 320*128 = 40960
    float* Bc      = tT + 40960;                 // 128*32
    float* Cc      = Bc + 4096;                  // 128*32

    float* y    = (float*)d_out;                 // [128,10240]
    float* hnew = y + (size_t)U_ * DIN;          // [128,10240,32]

    dim3 tb(32, 8);
    transpose_kernel<<<dim3(DIN / 32, U_ / 32), tb, 0, stream>>>(x, xT);
    if (big) {
        gemmA_kernel<64><<<12 * 64, 128, 0, stream>>>(xT, Wd, Wb, Wc, partial);
        reduce_kernel<64><<<192, 256, 0, stream>>>(partial, tT, Bc, Cc);
    } else {
        gemmA_kernel<32><<<12 * 32, 128, 0, stream>>>(xT, Wd, Wb, Wc, partial);
        reduce_kernel<32><<<192, 256, 0, stream>>>(partial, tT, Bc, Cc);
    }
    delta_kernel<<<1280, 64, 0, stream>>>(tT, Wdt, bdt, delta);
    ssm_kernel  <<<40960, 256, 0, stream>>>(x, h, delta, Bc, Cc, A, Dv, y, hnew);
}

// Round 2
// 391.579 us; speedup vs baseline: 1.2313x; 1.0522x over previous
//
#include <hip/hip_runtime.h>

#define U_    128
#define DIN   10240
#define RANK  320
#define NS    32
#define NTOT  384          // 320 (t) + 32 (B) + 32 (C)

// -------------------------------------------------------------------------
// Kernel 0: transpose x[128,10240] -> xT[10240,128]. ~3 us. (control)
// -------------------------------------------------------------------------
__global__ __launch_bounds__(256) void transpose_kernel(
    const float* __restrict__ x, float* __restrict__ xT)
{
    __shared__ float tile[32][33];
    int kb = blockIdx.x * 32, ub = blockIdx.y * 32;
    int tx = threadIdx.x, ty = threadIdx.y;      // (32, 8)
#pragma unroll
    for (int i = 0; i < 32; i += 8)
        tile[ty + i][tx] = x[(size_t)(ub + ty + i) * DIN + kb + tx];
    __syncthreads();
#pragma unroll
    for (int i = 0; i < 32; i += 8)
        xT[(size_t)(kb + ty + i) * U_ + ub + tx] = tile[tx][ty + i];
}

// -------------------------------------------------------------------------
// Kernel 1: gemmA — partial[kc][n][u] = sum_{k in chunk} xT[k,u] * W[k,n].
// R2 fix: replace the scalar-load (K$) W-stream — 128 B of s_load per
// k-iter, compulsory-miss latency serialized on lgkmcnt — with an LDS
// stage (coalesced float4 vector loads, once per element) + uniform-addr
// ds_read_b128 broadcast (conflict-free, ~12 cyc).
//   - 256-thread blocks: 128 u x 2 k-halves; halves combined in-block via
//     LDS so slot count stays = KCC (ws budget unchanged vs R1).
//   - grid = 12 nt x KCC: 3 waves/SIMD at KCC=64.
//   - id = nt*KCC+kc: same-kc blocks (sharing the 80 KB xT chunk) are
//     congruent mod 8 -> same XCD L2.
// -------------------------------------------------------------------------
template<int KCC>
__global__ __launch_bounds__(256) void gemmA_kernel(
    const float* __restrict__ xT,
    const float* __restrict__ Wd, const float* __restrict__ Wb,
    const float* __restrict__ Wc,
    float* __restrict__ partial)
{
    constexpr int KCH   = DIN / KCC;      // 160 (A-tier) / 320 (B-tier)
    constexpr int KHALF = KCH / 2;
    __shared__ float Wl[KCH][32];         // 20 KB / 40 KB

    int b  = blockIdx.x;                  // nt*KCC + kc
    int nt = b / KCC;
    int kc = b % KCC;
    int n0 = nt * 32;
    int k0 = kc * KCH;

    const float* W; int ldw, c0;
    if (nt < 10)       { W = Wd; ldw = RANK; c0 = n0; }
    else if (nt == 10) { W = Wb; ldw = NS;   c0 = 0;  }
    else               { W = Wc; ldw = NS;   c0 = 0;  }

    // stage W chunk: rows of 32 floats, float4 granularity, coalesced
    for (int i4 = threadIdx.x; i4 < KCH * 8; i4 += 256) {
        int r = i4 >> 3;
        int c = (i4 & 7) * 4;
        *(float4*)&Wl[r][c] =
            *(const float4*)&W[(size_t)(k0 + r) * ldw + c0 + c];
    }
    __syncthreads();

    int u    = threadIdx.x & 127;
    int half = threadIdx.x >> 7;

    float acc[32];
#pragma unroll
    for (int j = 0; j < 32; ++j) acc[j] = 0.f;

    const float* xp = xT + (size_t)(k0 + half * KHALF) * U_ + u;
    int kbase = half * KHALF;

#pragma unroll 8
    for (int k = 0; k < KHALF; ++k) {
        float xv = xp[(size_t)k * U_];                 // coalesced 512 B
        const float4* wr = (const float4*)&Wl[kbase + k][0];  // uniform -> bcast
#pragma unroll
        for (int j4 = 0; j4 < 8; ++j4) {
            float4 w = wr[j4];
            acc[j4 * 4 + 0] += xv * w.x;
            acc[j4 * 4 + 1] += xv * w.y;
            acc[j4 * 4 + 2] += xv * w.z;
            acc[j4 * 4 + 3] += xv * w.w;
        }
    }

    // in-block half-combine (reuse Wl; need 16 KB, have >=20 KB)
    __syncthreads();
    float* comb = &Wl[0][0];
    if (half == 1) {
#pragma unroll
        for (int j = 0; j < 32; ++j) comb[j * 128 + u] = acc[j];  // conflict-free
    }
    __syncthreads();
    if (half == 0) {
        float* out = partial + (size_t)kc * (NTOT * U_) + (size_t)n0 * U_ + u;
#pragma unroll
        for (int j = 0; j < 32; ++j)
            out[(size_t)j * U_] = acc[j] + comb[j * 128 + u];     // coalesced
    }
}

// -------------------------------------------------------------------------
// Kernel 2: reduce KCC k-chunk partials -> tT[320,128], B[128,32], C[128,32].
// -------------------------------------------------------------------------
template<int KCC>
__global__ __launch_bounds__(256) void reduce_kernel(
    const float* __restrict__ partial, float* __restrict__ tT,
    float* __restrict__ Bc, float* __restrict__ Cc)
{
    int e = blockIdx.x * 256 + threadIdx.x;      // 0..49151
    float s = 0.f;
#pragma unroll 8
    for (int kc = 0; kc < KCC; ++kc)
        s += partial[(size_t)kc * (NTOT * U_) + e];
    int n = e >> 7, u = e & 127;                 // e = n*128 + u
    if (n < RANK)            tT[e] = s;
    else if (n < RANK + NS)  Bc[u * NS + (n - RANK)] = s;
    else                     Cc[u * NS + (n - RANK - NS)] = s;
}

// -------------------------------------------------------------------------
// Kernel 3: delta = softplus(t @ W_dt + b_dt).
// R2 fix: tT operand staged in LDS (10 KB slice per block) and read back
// uniform-addr float4 (broadcast) instead of per-r scalar-load chains.
//   - u-tile 8, d-tile 128: grid 80x16 = 1280 blocks x 2 waves
//     = 2.5 waves/SIMD, 5 blocks/CU.
//   - same-dt blocks (sharing the 160 KB Wdt d-slice) have ids congruent
//     mod 8 (stride 80) -> same XCD L2; Wdt HBM traffic ~13 MB once.
// -------------------------------------------------------------------------
__global__ __launch_bounds__(128) void delta_kernel(
    const float* __restrict__ tT, const float* __restrict__ Wdt,
    const float* __restrict__ b_dt, float* __restrict__ delta)
{
    __shared__ float ts[RANK][8];                // 10 KB
    int b   = blockIdx.x;                        // ut*80 + dt
    int dt_ = b % 80, ut = b / 80;
    int d   = dt_ * 128 + threadIdx.x;
    int u0  = ut * 8;

    for (int i4 = threadIdx.x; i4 < RANK * 2; i4 += 128) {
        int r = i4 >> 1, c = (i4 & 1) * 4;
        *(float4*)&ts[r][c] = *(const float4*)&tT[(size_t)r * U_ + u0 + c];
    }
    __syncthreads();

    float bias = b_dt[d];
    float acc[8];
#pragma unroll
    for (int i = 0; i < 8; ++i) acc[i] = bias;

#pragma unroll 4
    for (int r = 0; r < RANK; ++r) {
        float w = Wdt[(size_t)r * DIN + d];      // coalesced 512 B / block
        const float4* tp = (const float4*)&ts[r][0];   // uniform -> bcast
        float4 t0 = tp[0], t1 = tp[1];
        acc[0] += w * t0.x; acc[1] += w * t0.y;
        acc[2] += w * t0.z; acc[3] += w * t0.w;
        acc[4] += w * t1.x; acc[5] += w * t1.y;
        acc[6] += w * t1.z; acc[7] += w * t1.w;
    }
#pragma unroll
    for (int i = 0; i < 8; ++i) {
        float z = acc[i];
        float sp = (z > 20.f) ? z : log1pf(__expf(z));
        delta[(size_t)(u0 + i) * DIN + d] = sp;  // coalesced
    }
}

// -------------------------------------------------------------------------
// Kernel 4: state update (memory-bound, ~353 MB HBM). UNCHANGED (control).
// -------------------------------------------------------------------------
__global__ __launch_bounds__(256) void ssm_kernel(
    const float* __restrict__ x, const float* __restrict__ h,
    const float* __restrict__ delta,
    const float* __restrict__ Bc, const float* __restrict__ Cc,
    const float* __restrict__ A, const float* __restrict__ Dvec,
    float* __restrict__ y, float* __restrict__ hnew)
{
    int idx4 = blockIdx.x * 256 + threadIdx.x;   // float4 index
    int n4 = idx4 & 7;
    int ud = idx4 >> 3;
    int d = ud % DIN;
    int u = ud / DIN;

    float dlt = delta[ud];
    float xv  = x[ud];

    float4 hv = ((const float4*)h)[idx4];
    float4 av = ((const float4*)A)[(size_t)d * 8 + n4];
    float4 bv = ((const float4*)Bc)[u * 8 + n4];
    float4 cv = ((const float4*)Cc)[u * 8 + n4];

    float dx = dlt * xv;
    float4 hn;
    hn.x = __expf(dlt * av.x) * hv.x + dx * bv.x;
    hn.y = __expf(dlt * av.y) * hv.y + dx * bv.y;
    hn.z = __expf(dlt * av.z) * hv.z + dx * bv.z;
    hn.w = __expf(dlt * av.w) * hv.w + dx * bv.w;

    ((float4*)hnew)[idx4] = hn;

    float p = hn.x * cv.x + hn.y * cv.y + hn.z * cv.z + hn.w * cv.w;
    p += __shfl_xor(p, 4, 8);
    p += __shfl_xor(p, 2, 8);
    p += __shfl_xor(p, 1, 8);
    if (n4 == 0)
        y[ud] = p + Dvec[d] * xv;
}

// -------------------------------------------------------------------------
extern "C" void kernel_launch(void* const* d_in, const int* in_sizes, int n_in,
                              void* d_out, int out_size, void* d_ws, size_t ws_size,
                              hipStream_t stream)
{
    const float* x   = (const float*)d_in[0];
    const float* h   = (const float*)d_in[1];
    const float* Wd  = (const float*)d_in[2];
    const float* Wdt = (const float*)d_in[3];
    const float* bdt = (const float*)d_in[4];
    const float* Wb  = (const float*)d_in[5];
    const float* Wc  = (const float*)d_in[6];
    const float* A   = (const float*)d_in[7];
    const float* Dv  = (const float*)d_in[8];

    // Tier A (KCC=64): ws = 1310720 + 64*384*128 + 49152 = 4,505,600 floats
    // (18.0 MB).  Tier B (KCC=32): 2,932,736 floats (11.7 MB, R0-proven fit).
    const bool big = ws_size >= (size_t)4505600 * 4;
    const size_t partial_elems = (size_t)(big ? 64 : 32) * NTOT * U_;

    float* ws      = (float*)d_ws;
    float* xT      = ws;                         // 10240*128 = 1310720
    float* partial = ws + 1310720;               // KCC*384*128
    float* delta   = partial;                    // ALIAS: partial dead after reduce
    float* tT      = partial + partial_elems;    // 320*128 = 40960
    float* Bc      = tT + 40960;                 // 128*32
    float* Cc      = Bc + 4096;                  // 128*32

    float* y    = (float*)d_out;                 // [128,10240]
    float* hnew = y + (size_t)U_ * DIN;          // [128,10240,32]

    dim3 tb(32, 8);
    transpose_kernel<<<dim3(DIN / 32, U_ / 32), tb, 0, stream>>>(x, xT);
    if (big) {
        gemmA_kernel<64><<<12 * 64, 256, 0, stream>>>(xT, Wd, Wb, Wc, partial);
        reduce_kernel<64><<<192, 256, 0, stream>>>(partial, tT, Bc, Cc);
    } else {
        gemmA_kernel<32><<<12 * 32, 256, 0, stream>>>(xT, Wd, Wb, Wc, partial);
        reduce_kernel<32><<<192, 256, 0, stream>>>(partial, tT, Bc, Cc);
    }
    delta_kernel<<<80 * 16, 128, 0, stream>>>(tT, Wdt, bdt, delta);
    ssm_kernel  <<<40960, 256, 0, stream>>>(x, h, delta, Bc, Cc, A, Dv, y, hnew);
}